// Round 1
// baseline (592.902 us; speedup 1.0000x reference)
//
#include <hip/hip_runtime.h>
#include <math.h>

#define N_NODES 10000

// ---------------- CSR build ----------------

__global__ void zero_k(int* __restrict__ p, int n) {
  int i = blockIdx.x * blockDim.x + threadIdx.x;
  if (i < n) p[i] = 0;
}

__global__ void count_k(const int* __restrict__ dst, int E, int* __restrict__ cnt) {
  int i = blockIdx.x * blockDim.x + threadIdx.x;
  if (i < E) atomicAdd(&cnt[dst[i]], 1);
}

// single-block exclusive scan over n (<= a few 10k), writes rowptr[0..n] and nxt[0..n-1]
__global__ void scan_k(const int* __restrict__ cnt, int* __restrict__ rowptr,
                       int* __restrict__ nxt, int n) {
  __shared__ int lds[1024];
  __shared__ int carry_s;
  const int t = threadIdx.x;
  if (t == 0) carry_s = 0;
  __syncthreads();
  for (int base = 0; base < n; base += 1024) {
    int v = (base + t < n) ? cnt[base + t] : 0;
    lds[t] = v;
    __syncthreads();
    for (int off = 1; off < 1024; off <<= 1) {
      int add = (t >= off) ? lds[t - off] : 0;
      __syncthreads();
      lds[t] += add;
      __syncthreads();
    }
    int excl = lds[t] - v + carry_s;
    if (base + t < n) { rowptr[base + t] = excl; nxt[base + t] = excl; }
    int incl_last = lds[1023];
    __syncthreads();
    if (t == 0) carry_s += incl_last;
    __syncthreads();
  }
  if (t == 0) rowptr[n] = carry_s;
}

__global__ void fill_k(const int* __restrict__ src, const int* __restrict__ dst,
                       int E, int* __restrict__ nxt, int* __restrict__ csr_src) {
  int i = blockIdx.x * blockDim.x + threadIdx.x;
  if (i < E) {
    int pos = atomicAdd(&nxt[dst[i]], 1);
    csr_src[pos] = src[i];
  }
}

// ---------------- dense GEMM: Y[N,O] = X[N,K] @ W[K,O] ----------------
// block = O threads, computes 8 rows; x rows staged in LDS (broadcast reads),
// W read coalesced (column index = threadIdx), reused across the 8 rows.

template <int K, int O>
__global__ void __launch_bounds__(O) gemm8_k(const float* __restrict__ X,
                                             const float* __restrict__ W,
                                             float* __restrict__ Y) {
  __shared__ float xs[8][K];
  const int r0 = blockIdx.x * 8;
  const int t = threadIdx.x;
  for (int idx = t; idx < 8 * K; idx += O) {
    xs[idx / K][idx % K] = X[r0 * K + idx];
  }
  __syncthreads();
  float acc[8];
#pragma unroll
  for (int r = 0; r < 8; ++r) acc[r] = 0.f;
  for (int k = 0; k < K; ++k) {
    float w = W[k * O + t];
#pragma unroll
    for (int r = 0; r < 8; ++r) acc[r] += xs[r][k] * w;
  }
#pragma unroll
  for (int r = 0; r < 8; ++r) Y[(r0 + r) * O + t] = acc[r];
}

// ---------------- per-dst-node online-softmax aggregation ----------------
// one wave (64 lanes) per destination node; C = O/64 f32 chunks per lane.
// e = att . leaky_relu(xl[src] + xr[dst]); online softmax over incoming edges;
// acc += w * xl[src]; out = acc/s + b, relu (+ sigmoid on final layer).

template <int C, bool FINAL>
__global__ void agg_k(const float* __restrict__ xl, const float* __restrict__ xr,
                      const float* __restrict__ att, const float* __restrict__ bias,
                      const int* __restrict__ rowptr, const int* __restrict__ csr_src,
                      float* __restrict__ out) {
  const int wid = (int)((blockIdx.x * blockDim.x + threadIdx.x) >> 6);
  const int lane = threadIdx.x & 63;
  if (wid >= N_NODES) return;
  const int O = C * 64;
  float xrv[C], attv[C], acc[C];
#pragma unroll
  for (int c = 0; c < C; ++c) {
    xrv[c] = xr[wid * O + c * 64 + lane];
    attv[c] = att[c * 64 + lane];
    acc[c] = 0.f;
  }
  float m = -INFINITY, s = 0.f;
  const int beg = rowptr[wid];
  const int end = rowptr[wid + 1];
  for (int e = beg; e < end; ++e) {
    const int j = csr_src[e];
    float xlv[C];
    float p = 0.f;
#pragma unroll
    for (int c = 0; c < C; ++c) {
      xlv[c] = xl[j * O + c * 64 + lane];
      float t2 = xlv[c] + xrv[c];
      t2 = (t2 > 0.f) ? t2 : 0.2f * t2;
      p += attv[c] * t2;
    }
#pragma unroll
    for (int off = 32; off > 0; off >>= 1) p += __shfl_xor(p, off, 64);
    // p is wave-uniform now; online softmax update
    if (p > m) {
      const float f = __expf(m - p);  // exp(-inf)=0 on first edge
      s *= f;
#pragma unroll
      for (int c = 0; c < C; ++c) acc[c] *= f;
      m = p;
    }
    const float w = __expf(p - m);
    s += w;
#pragma unroll
    for (int c = 0; c < C; ++c) acc[c] += w * xlv[c];
  }
  const float inv = 1.f / (s + 1e-16f);
#pragma unroll
  for (int c = 0; c < C; ++c) {
    float v = acc[c] * inv + bias[c * 64 + lane];
    v = (v > 0.f) ? v : 0.f;  // relu
    if (FINAL) v = 1.f / (1.f + __expf(-v));  // sigmoid(relu(z))
    out[wid * O + c * 64 + lane] = v;
  }
}

// ---------------- launch ----------------

extern "C" void kernel_launch(void* const* d_in, const int* in_sizes, int n_in,
                              void* d_out, int out_size, void* d_ws, size_t ws_size,
                              hipStream_t stream) {
  const float* x = (const float*)d_in[0];
  const int* ei = (const int*)d_in[1];
  const int E = in_sizes[1] / 2;
  const int* src = ei;
  const int* dst = ei + E;
  const float* Wl[3] = {(const float*)d_in[2], (const float*)d_in[6], (const float*)d_in[10]};
  const float* Wr[3] = {(const float*)d_in[3], (const float*)d_in[7], (const float*)d_in[11]};
  const float* att[3] = {(const float*)d_in[4], (const float*)d_in[8], (const float*)d_in[12]};
  const float* bia[3] = {(const float*)d_in[5], (const float*)d_in[9], (const float*)d_in[13]};

  char* ws = (char*)d_ws;
  size_t off = 0;
  auto alloc = [&](size_t bytes) -> void* {
    void* p = ws + off;
    off = (off + bytes + 255) & ~(size_t)255;
    return p;
  };
  int* cnt = (int*)alloc((size_t)N_NODES * sizeof(int));
  int* rowptr = (int*)alloc((size_t)(N_NODES + 1) * sizeof(int));
  int* nxt = (int*)alloc((size_t)N_NODES * sizeof(int));
  int* csr_src = (int*)alloc((size_t)E * sizeof(int));
  float* xl = (float*)alloc((size_t)N_NODES * 256 * sizeof(float));
  float* xr = (float*)alloc((size_t)N_NODES * 256 * sizeof(float));
  float* cur = (float*)alloc((size_t)N_NODES * 256 * sizeof(float));

  // ---- CSR by dst (recomputed every call; no cached state) ----
  zero_k<<<(N_NODES + 255) / 256, 256, 0, stream>>>(cnt, N_NODES);
  count_k<<<(E + 255) / 256, 256, 0, stream>>>(dst, E, cnt);
  scan_k<<<1, 1024, 0, stream>>>(cnt, rowptr, nxt, N_NODES);
  fill_k<<<(E + 255) / 256, 256, 0, stream>>>(src, dst, E, nxt, csr_src);

  const int aggBlocks = (N_NODES * 64 + 255) / 256;

  // ---- layer 0: 128 -> 256 ----
  gemm8_k<128, 256><<<N_NODES / 8, 256, 0, stream>>>(x, Wl[0], xl);
  gemm8_k<128, 256><<<N_NODES / 8, 256, 0, stream>>>(x, Wr[0], xr);
  agg_k<4, false><<<aggBlocks, 256, 0, stream>>>(xl, xr, att[0], bia[0], rowptr, csr_src, cur);

  // ---- layer 1: 256 -> 256 ----
  gemm8_k<256, 256><<<N_NODES / 8, 256, 0, stream>>>(cur, Wl[1], xl);
  gemm8_k<256, 256><<<N_NODES / 8, 256, 0, stream>>>(cur, Wr[1], xr);
  agg_k<4, false><<<aggBlocks, 256, 0, stream>>>(xl, xr, att[1], bia[1], rowptr, csr_src, cur);

  // ---- layer 2: 256 -> 128 ----
  gemm8_k<256, 128><<<N_NODES / 8, 128, 0, stream>>>(cur, Wl[2], xl);
  gemm8_k<256, 128><<<N_NODES / 8, 128, 0, stream>>>(cur, Wr[2], xr);
  agg_k<2, true><<<aggBlocks, 256, 0, stream>>>(xl, xr, att[2], bia[2], rowptr, csr_src,
                                                (float*)d_out);
}

// Round 2
// 486.113 us; speedup vs baseline: 1.2197x; 1.2197x over previous
//
#include <hip/hip_runtime.h>
#include <math.h>

#define N_NODES 10000

// ---------------- CSR build ----------------

__global__ void zero_k(int* __restrict__ p, int n) {
  int i = blockIdx.x * blockDim.x + threadIdx.x;
  if (i < n) p[i] = 0;
}

__global__ void count_k(const int* __restrict__ dst, int E, int* __restrict__ cnt) {
  int i = blockIdx.x * blockDim.x + threadIdx.x;
  if (i < E) atomicAdd(&cnt[dst[i]], 1);
}

// single-block exclusive scan over n, writes rowptr[0..n] and nxt[0..n-1]
__global__ void scan_k(const int* __restrict__ cnt, int* __restrict__ rowptr,
                       int* __restrict__ nxt, int n) {
  __shared__ int lds[1024];
  __shared__ int carry_s;
  const int t = threadIdx.x;
  if (t == 0) carry_s = 0;
  __syncthreads();
  for (int base = 0; base < n; base += 1024) {
    int v = (base + t < n) ? cnt[base + t] : 0;
    lds[t] = v;
    __syncthreads();
    for (int off = 1; off < 1024; off <<= 1) {
      int add = (t >= off) ? lds[t - off] : 0;
      __syncthreads();
      lds[t] += add;
      __syncthreads();
    }
    int excl = lds[t] - v + carry_s;
    if (base + t < n) { rowptr[base + t] = excl; nxt[base + t] = excl; }
    int incl_last = lds[1023];
    __syncthreads();
    if (t == 0) carry_s += incl_last;
    __syncthreads();
  }
  if (t == 0) rowptr[n] = carry_s;
}

__global__ void fill_k(const int* __restrict__ src, const int* __restrict__ dst,
                       int E, int* __restrict__ nxt, int* __restrict__ csr_src) {
  int i = blockIdx.x * blockDim.x + threadIdx.x;
  if (i < E) {
    int pos = atomicAdd(&nxt[dst[i]], 1);
    csr_src[pos] = src[i];
  }
}

// ---------------- dense GEMM: Y[N,O] = X[N,K] @ W[K,O] ----------------
// threads = O/2 (2 cols/thread, float2 W loads), ROWS rows per block.
// X row values are wave-uniform -> scalar loads (no LDS, no barrier).
// Per k: 1x 8B W load + 2*ROWS fma.

template <int K, int O, int ROWS>
__global__ void __launch_bounds__(O / 2) gemmv2_k(const float* __restrict__ X,
                                                  const float* __restrict__ W,
                                                  float* __restrict__ Y) {
  const int r0 = blockIdx.x * ROWS;
  const int t = threadIdx.x;  // 0 .. O/2-1
  const int c0 = 2 * t;
  float acc[ROWS][2];
#pragma unroll
  for (int r = 0; r < ROWS; ++r) { acc[r][0] = 0.f; acc[r][1] = 0.f; }
#pragma unroll 8
  for (int k = 0; k < K; ++k) {
    const float2 w2 = *(const float2*)&W[k * O + c0];
#pragma unroll
    for (int r = 0; r < ROWS; ++r) {
      const float xv = X[(r0 + r) * K + k];  // wave-uniform -> s_load
      acc[r][0] = fmaf(xv, w2.x, acc[r][0]);
      acc[r][1] = fmaf(xv, w2.y, acc[r][1]);
    }
  }
#pragma unroll
  for (int r = 0; r < ROWS; ++r) {
    *(float2*)&Y[(r0 + r) * O + c0] = make_float2(acc[r][0], acc[r][1]);
  }
}

// ---------------- per-dst-node online-softmax aggregation v2 ----------------
// block = 256 threads = 4 waves = 2 nodes (2 waves per node, halves of the
// edge list, merged via LDS). Within a wave: lane = (e_sub in [0,4) | cl in
// [0,16)); 4 edges processed per step, 16 channels per lane per edge.
// Score reduce: xor {4,8,16,32} sums within each edge's 16 lanes (4 steps for
// all 4 edges); xor {1,2} gives cross-edge max / weight-sum. One online
// rescale per 4-edge group.

template <int O, bool FINAL>
__global__ void __launch_bounds__(256, 4) agg2_k(
    const float* __restrict__ xl, const float* __restrict__ xr,
    const float* __restrict__ att, const float* __restrict__ bias,
    const int* __restrict__ rowptr, const int* __restrict__ csr_src,
    float* __restrict__ out) {
  constexpr int NCH = O / 16;  // channels per lane
  __shared__ float sm[2], ss[2], sacc[2][O];
  const int tid = threadIdx.x;
  const int wv = tid >> 6;
  const int lane = tid & 63;
  const int nloc = wv >> 1;  // node within block
  const int half = wv & 1;   // which half of the edge list
  const int node = blockIdx.x * 2 + nloc;
  const int e_sub = lane & 3;
  const int cl = lane >> 2;  // 0..15

  float xrv[NCH], attv[NCH], acc[NCH];
#pragma unroll
  for (int k = 0; k < NCH; ++k) {
    const int ch = k * 16 + cl;
    xrv[k] = xr[node * O + ch];
    attv[k] = att[ch];
    acc[k] = 0.f;
  }
  const int beg = rowptr[node];
  const int end = rowptr[node + 1];
  const int cnt = end - beg;
  const int h0 = (cnt + 1) >> 1;
  const int b = half ? beg + h0 : beg;
  const int e_end = half ? end : beg + h0;

  float m = -INFINITY, s = 0.f;
  for (int eg = b; eg < e_end; eg += 4) {
    const int ei = eg + e_sub;
    const bool valid = (ei < e_end);
    const int j = csr_src[valid ? ei : e_end - 1];
    float xlv[NCH];
    float p = 0.f;
#pragma unroll
    for (int k = 0; k < NCH; ++k) {
      xlv[k] = xl[j * O + k * 16 + cl];
      float t2 = xlv[k] + xrv[k];
      t2 = (t2 > 0.f) ? t2 : 0.2f * t2;
      p = fmaf(attv[k], t2, p);
    }
    if (!valid) p = -INFINITY;
    // sum over the 16 lanes of each edge (all 4 edges at once)
    p += __shfl_xor(p, 4, 64);
    p += __shfl_xor(p, 8, 64);
    p += __shfl_xor(p, 16, 64);
    p += __shfl_xor(p, 32, 64);
    // cross-edge max and per-lane weight
    float q = fmaxf(p, __shfl_xor(p, 1, 64));
    q = fmaxf(q, __shfl_xor(q, 2, 64));
    const float m_new = fmaxf(m, q);
    const float f = __expf(m - m_new);  // exp(-inf)=0 on first group
    const float w = __expf(p - m_new);  // 0 for invalid edges
    float ws = w + __shfl_xor(w, 1, 64);
    ws += __shfl_xor(ws, 2, 64);
    s = s * f + ws;
#pragma unroll
    for (int k = 0; k < NCH; ++k) acc[k] = acc[k] * f + w * xlv[k];
    m = m_new;
  }
  // collapse the 4 per-edge-residue copies of acc
#pragma unroll
  for (int k = 0; k < NCH; ++k) {
    acc[k] += __shfl_xor(acc[k], 1, 64);
    acc[k] += __shfl_xor(acc[k], 2, 64);
  }
  // half 1 publishes; half 0 merges and writes
  if (half == 1) {
    if (lane == 0) { sm[nloc] = m; ss[nloc] = s; }
    if (e_sub == 0) {
#pragma unroll
      for (int k = 0; k < NCH; ++k) sacc[nloc][k * 16 + cl] = acc[k];
    }
  }
  __syncthreads();
  if (half == 0) {
    const float m1 = sm[nloc], s1 = ss[nloc];
    const float mt = fmaxf(m, m1);
    const float f0 = __expf(m - mt);
    const float f1 = __expf(m1 - mt);  // 0 if half1 empty (m1=-inf)
    const float st = s * f0 + s1 * f1;
    const float inv = 1.f / (st + 1e-16f);
    if (e_sub == 0) {
#pragma unroll
      for (int k = 0; k < NCH; ++k) {
        const int ch = k * 16 + cl;
        float v = (acc[k] * f0 + sacc[nloc][ch] * f1) * inv + bias[ch];
        v = (v > 0.f) ? v : 0.f;  // relu
        if (FINAL) v = 1.f / (1.f + __expf(-v));  // sigmoid
        out[node * O + ch] = v;
      }
    }
  }
}

// ---------------- launch ----------------

extern "C" void kernel_launch(void* const* d_in, const int* in_sizes, int n_in,
                              void* d_out, int out_size, void* d_ws, size_t ws_size,
                              hipStream_t stream) {
  const float* x = (const float*)d_in[0];
  const int* ei = (const int*)d_in[1];
  const int E = in_sizes[1] / 2;
  const int* src = ei;
  const int* dst = ei + E;
  const float* Wl[3] = {(const float*)d_in[2], (const float*)d_in[6], (const float*)d_in[10]};
  const float* Wr[3] = {(const float*)d_in[3], (const float*)d_in[7], (const float*)d_in[11]};
  const float* att[3] = {(const float*)d_in[4], (const float*)d_in[8], (const float*)d_in[12]};
  const float* bia[3] = {(const float*)d_in[5], (const float*)d_in[9], (const float*)d_in[13]};

  char* ws = (char*)d_ws;
  size_t off = 0;
  auto alloc = [&](size_t bytes) -> void* {
    void* p = ws + off;
    off = (off + bytes + 255) & ~(size_t)255;
    return p;
  };
  int* cnt = (int*)alloc((size_t)N_NODES * sizeof(int));
  int* rowptr = (int*)alloc((size_t)(N_NODES + 1) * sizeof(int));
  int* nxt = (int*)alloc((size_t)N_NODES * sizeof(int));
  int* csr_src = (int*)alloc((size_t)E * sizeof(int));
  float* xl = (float*)alloc((size_t)N_NODES * 256 * sizeof(float));
  float* xr = (float*)alloc((size_t)N_NODES * 256 * sizeof(float));
  float* cur = (float*)alloc((size_t)N_NODES * 256 * sizeof(float));

  // ---- CSR by dst (recomputed every call; stateless) ----
  zero_k<<<(N_NODES + 255) / 256, 256, 0, stream>>>(cnt, N_NODES);
  count_k<<<(E + 255) / 256, 256, 0, stream>>>(dst, E, cnt);
  scan_k<<<1, 1024, 0, stream>>>(cnt, rowptr, nxt, N_NODES);
  fill_k<<<(E + 255) / 256, 256, 0, stream>>>(src, dst, E, nxt, csr_src);

  // ---- layer 0: 128 -> 256 ----
  gemmv2_k<128, 256, 8><<<N_NODES / 8, 128, 0, stream>>>(x, Wl[0], xl);
  gemmv2_k<128, 256, 8><<<N_NODES / 8, 128, 0, stream>>>(x, Wr[0], xr);
  agg2_k<256, false><<<N_NODES / 2, 256, 0, stream>>>(xl, xr, att[0], bia[0], rowptr, csr_src, cur);

  // ---- layer 1: 256 -> 256 ----
  gemmv2_k<256, 256, 8><<<N_NODES / 8, 128, 0, stream>>>(cur, Wl[1], xl);
  gemmv2_k<256, 256, 8><<<N_NODES / 8, 128, 0, stream>>>(cur, Wr[1], xr);
  agg2_k<256, false><<<N_NODES / 2, 256, 0, stream>>>(xl, xr, att[1], bia[1], rowptr, csr_src, cur);

  // ---- layer 2: 256 -> 128 ----
  gemmv2_k<256, 128, 4><<<N_NODES / 4, 64, 0, stream>>>(cur, Wl[2], xl);
  gemmv2_k<256, 128, 4><<<N_NODES / 4, 64, 0, stream>>>(cur, Wr[2], xr);
  agg2_k<128, true><<<N_NODES / 2, 256, 0, stream>>>(xl, xr, att[2], bia[2], rowptr, csr_src,
                                                     (float*)d_out);
}

// Round 3
// 427.352 us; speedup vs baseline: 1.3874x; 1.1375x over previous
//
#include <hip/hip_runtime.h>
#include <hip/hip_bf16.h>
#include <math.h>

#define N_NODES 10000

typedef __attribute__((ext_vector_type(8))) short short8;
typedef __attribute__((ext_vector_type(4))) float f32x4;

// ---------------- CSR build ----------------

__global__ void zero_k(int* __restrict__ p, int n) {
  int i = blockIdx.x * blockDim.x + threadIdx.x;
  if (i < n) p[i] = 0;
}

__global__ void count_k(const int* __restrict__ dst, int E, int* __restrict__ cnt) {
  int i = blockIdx.x * blockDim.x + threadIdx.x;
  if (i < E) atomicAdd(&cnt[dst[i]], 1);
}

__global__ void scan_k(const int* __restrict__ cnt, int* __restrict__ rowptr,
                       int* __restrict__ nxt, int n) {
  __shared__ int lds[1024];
  __shared__ int carry_s;
  const int t = threadIdx.x;
  if (t == 0) carry_s = 0;
  __syncthreads();
  for (int base = 0; base < n; base += 1024) {
    int v = (base + t < n) ? cnt[base + t] : 0;
    lds[t] = v;
    __syncthreads();
    for (int off = 1; off < 1024; off <<= 1) {
      int add = (t >= off) ? lds[t - off] : 0;
      __syncthreads();
      lds[t] += add;
      __syncthreads();
    }
    int excl = lds[t] - v + carry_s;
    if (base + t < n) { rowptr[base + t] = excl; nxt[base + t] = excl; }
    int incl_last = lds[1023];
    __syncthreads();
    if (t == 0) carry_s += incl_last;
    __syncthreads();
  }
  if (t == 0) rowptr[n] = carry_s;
}

__global__ void fill_k(const int* __restrict__ src, const int* __restrict__ dst,
                       int E, int* __restrict__ nxt, int* __restrict__ csr_src) {
  int i = blockIdx.x * blockDim.x + threadIdx.x;
  if (i < E) {
    int pos = atomicAdd(&nxt[dst[i]], 1);
    csr_src[pos] = src[i];
  }
}

// ---------------- conversions ----------------

__global__ void f2b_k(const float* __restrict__ src, __hip_bfloat16* __restrict__ dst, int n) {
  int i = blockIdx.x * blockDim.x + threadIdx.x;
  if (i < n) dst[i] = __float2bfloat16(src[i]);
}

// W [K][O] f32  ->  Wt [O][K] bf16, six matrices in one launch
struct WtArgs {
  const float* src[6];
  __hip_bfloat16* dst[6];
  int K[6];
  int O[6];
};

__global__ void wconv_k(WtArgs a) {
  const int m = blockIdx.y;
  const float* s = a.src[m];
  __hip_bfloat16* d = a.dst[m];
  const int K = a.K[m], O = a.O[m], n = K * O;
  for (int idx = blockIdx.x * 256 + threadIdx.x; idx < n; idx += gridDim.x * 256) {
    const int col = idx / K, k = idx - col * K;  // dst is [col][k]
    d[idx] = __float2bfloat16(s[k * O + col]);
  }
}

// ---------------- bf16 MFMA GEMM: Y[M,O] = Xb[M,K] @ Wt[O,K]^T ----------------
// block = 256 threads = 4 waves; wave w owns rows blockIdx.x*64 + w*16 .. +15,
// cols blockIdx.y*64 .. +63 (4 col-tiles of 16). blockIdx.z picks Wl/Wr.
// A-frag: lane l -> row (l&15), k = (l>>4)*8+j.  B^T-frag symmetric.
// C/D: col = lane&15, row = (lane>>4)*4 + reg  [guide m89/m91 verified].

template <int K, int O>
__global__ void __launch_bounds__(256) mfma_gemm_k(
    const ushort* __restrict__ Xb, const ushort* __restrict__ WtL,
    const ushort* __restrict__ WtR, float* __restrict__ xl, float* __restrict__ xr) {
  const int wv = threadIdx.x >> 6, lane = threadIdx.x & 63;
  const int rowBase = blockIdx.x * 64 + wv * 16;
  const int colBase = blockIdx.y * 64;
  const ushort* __restrict__ Wt = blockIdx.z ? WtR : WtL;
  float* __restrict__ Y = blockIdx.z ? xr : xl;
  const int lr = lane & 15, lh = lane >> 4;

  int arow = rowBase + lr;
  if (arow >= N_NODES) arow = 0;  // clamp (loads only; stores guarded)
  const ushort* __restrict__ aptr = Xb + (size_t)arow * K + lh * 8;
  const ushort* __restrict__ bptr = Wt + (size_t)(colBase + lr) * K + lh * 8;

  f32x4 acc[4] = {f32x4{0,0,0,0}, f32x4{0,0,0,0}, f32x4{0,0,0,0}, f32x4{0,0,0,0}};
#pragma unroll
  for (int kt = 0; kt < K; kt += 32) {
    const short8 a = *(const short8*)(aptr + kt);
#pragma unroll
    for (int c = 0; c < 4; ++c) {
      const short8 b = *(const short8*)(bptr + (size_t)c * 16 * K + kt);
      acc[c] = __builtin_amdgcn_mfma_f32_16x16x32_bf16(a, b, acc[c], 0, 0, 0);
    }
  }
#pragma unroll
  for (int c = 0; c < 4; ++c) {
#pragma unroll
    for (int q = 0; q < 4; ++q) {
      const int r = rowBase + lh * 4 + q;
      if (r < N_NODES) Y[(size_t)r * O + colBase + c * 16 + lr] = acc[c][q];
    }
  }
}

// ---------------- per-dst-node online-softmax aggregation v3 ----------------
// 4 waves/block = 2 nodes x 2 half-edge-lists. lane = (e_sub in [0,4) | cl in
// [0,16)); lane's channels are CONTIGUOUS: ch = cl*NCH + k -> float4 gathers.
// leaky fold: att*leaky(t) = (0.6 att) t + (0.4 att)|t|. Depth-2 prefetch.

template <int O, bool FINAL>
__global__ void __launch_bounds__(256, 4) agg3_k(
    const float* __restrict__ xl, const float* __restrict__ xr,
    const float* __restrict__ att, const float* __restrict__ bias,
    const int* __restrict__ rowptr, const int* __restrict__ csr_src,
    void* __restrict__ outp) {
  constexpr int NCH = O / 16;  // 16 or 8 channels per lane
  constexpr int NV = NCH / 4;  // float4 loads per row-slice
  __shared__ float sm[2], ss[2], sacc[2][O];
  const int tid = threadIdx.x;
  const int wv = tid >> 6;
  const int lane = tid & 63;
  const int nloc = wv >> 1;
  const int half = wv & 1;
  const int node = blockIdx.x * 2 + nloc;
  const int e_sub = lane & 3;
  const int cl = lane >> 2;
  const int ch0 = cl * NCH;

  float a6[NCH], a4[NCH], xrv[NCH], acc[NCH];
#pragma unroll
  for (int k = 0; k < NCH; ++k) {
    const float a = att[ch0 + k];
    a6[k] = 0.6f * a;
    a4[k] = 0.4f * a;
    xrv[k] = xr[(size_t)node * O + ch0 + k];
    acc[k] = 0.f;
  }
  const int beg = rowptr[node];
  const int end = rowptr[node + 1];
  const int h0 = (end - beg + 1) >> 1;
  const int b = half ? beg + h0 : beg;
  const int e_end = half ? end : beg + h0;

  float m = -INFINITY, s = 0.f;
  if (b < e_end) {
    float4 xcur[NV], xnxt[NV];
    {
      const int ei = b + e_sub;
      const int jj = csr_src[(ei < e_end) ? ei : e_end - 1];
      const float4* row = (const float4*)&xl[(size_t)jj * O + ch0];
#pragma unroll
      for (int v = 0; v < NV; ++v) xcur[v] = row[v];
    }
    for (int eg = b; eg < e_end; eg += 4) {
      // prefetch next group
      if (eg + 4 < e_end) {
        const int ei = eg + 4 + e_sub;
        const int jj = csr_src[(ei < e_end) ? ei : e_end - 1];
        const float4* row = (const float4*)&xl[(size_t)jj * O + ch0];
#pragma unroll
        for (int v = 0; v < NV; ++v) xnxt[v] = row[v];
      }
      const bool valid = (eg + e_sub < e_end);
      float p = 0.f;
#pragma unroll
      for (int v = 0; v < NV; ++v) {
        const float4 x4 = xcur[v];
        float t;
        t = x4.x + xrv[4 * v + 0]; p = fmaf(a6[4 * v + 0], t, p); p = fmaf(a4[4 * v + 0], fabsf(t), p);
        t = x4.y + xrv[4 * v + 1]; p = fmaf(a6[4 * v + 1], t, p); p = fmaf(a4[4 * v + 1], fabsf(t), p);
        t = x4.z + xrv[4 * v + 2]; p = fmaf(a6[4 * v + 2], t, p); p = fmaf(a4[4 * v + 2], fabsf(t), p);
        t = x4.w + xrv[4 * v + 3]; p = fmaf(a6[4 * v + 3], t, p); p = fmaf(a4[4 * v + 3], fabsf(t), p);
      }
      if (!valid) p = -INFINITY;
      p += __shfl_xor(p, 4, 64);
      p += __shfl_xor(p, 8, 64);
      p += __shfl_xor(p, 16, 64);
      p += __shfl_xor(p, 32, 64);
      float q = fmaxf(p, __shfl_xor(p, 1, 64));
      q = fmaxf(q, __shfl_xor(q, 2, 64));
      const float m_new = fmaxf(m, q);
      const float w = __expf(p - m_new);  // 0 for invalid lanes
      float ws = w + __shfl_xor(w, 1, 64);
      ws += __shfl_xor(ws, 2, 64);
      if (m_new > m) {  // wave-uniform; skip rescale when max unchanged
        const float f = __expf(m - m_new);
        s *= f;
#pragma unroll
        for (int k = 0; k < NCH; ++k) acc[k] *= f;
        m = m_new;
      }
      s += ws;
#pragma unroll
      for (int v = 0; v < NV; ++v) {
        const float4 x4 = xcur[v];
        acc[4 * v + 0] = fmaf(w, x4.x, acc[4 * v + 0]);
        acc[4 * v + 1] = fmaf(w, x4.y, acc[4 * v + 1]);
        acc[4 * v + 2] = fmaf(w, x4.z, acc[4 * v + 2]);
        acc[4 * v + 3] = fmaf(w, x4.w, acc[4 * v + 3]);
      }
#pragma unroll
      for (int v = 0; v < NV; ++v) xcur[v] = xnxt[v];
    }
  }
  // collapse 4 edge-residue copies
#pragma unroll
  for (int k = 0; k < NCH; ++k) {
    acc[k] += __shfl_xor(acc[k], 1, 64);
    acc[k] += __shfl_xor(acc[k], 2, 64);
  }
  if (half == 1) {
    if (lane == 0) { sm[nloc] = m; ss[nloc] = s; }
    if (e_sub == 0) {
#pragma unroll
      for (int k = 0; k < NCH; ++k) sacc[nloc][ch0 + k] = acc[k];
    }
  }
  __syncthreads();
  if (half == 0) {
    const float m1 = sm[nloc], s1 = ss[nloc];
    const float mt = fmaxf(m, m1);
    const float f0 = __expf(m - mt);
    const float f1 = __expf(m1 - mt);
    const float st = s * f0 + s1 * f1;
    const float inv = 1.f / (st + 1e-16f);
    if (e_sub == 0) {
#pragma unroll
      for (int k = 0; k < NCH; ++k) {
        const int ch = ch0 + k;
        float v = (acc[k] * f0 + sacc[nloc][ch] * f1) * inv + bias[ch];
        v = (v > 0.f) ? v : 0.f;  // relu
        if (FINAL) {
          ((float*)outp)[(size_t)node * O + ch] = 1.f / (1.f + __expf(-v));
        } else {
          ((__hip_bfloat16*)outp)[(size_t)node * O + ch] = __float2bfloat16(v);
        }
      }
    }
  }
}

// ---------------- launch ----------------

extern "C" void kernel_launch(void* const* d_in, const int* in_sizes, int n_in,
                              void* d_out, int out_size, void* d_ws, size_t ws_size,
                              hipStream_t stream) {
  const float* x = (const float*)d_in[0];
  const int* ei = (const int*)d_in[1];
  const int E = in_sizes[1] / 2;
  const int* src = ei;
  const int* dst = ei + E;
  const float* Wl[3] = {(const float*)d_in[2], (const float*)d_in[6], (const float*)d_in[10]};
  const float* Wr[3] = {(const float*)d_in[3], (const float*)d_in[7], (const float*)d_in[11]};
  const float* att[3] = {(const float*)d_in[4], (const float*)d_in[8], (const float*)d_in[12]};
  const float* bia[3] = {(const float*)d_in[5], (const float*)d_in[9], (const float*)d_in[13]};

  char* ws = (char*)d_ws;
  size_t off = 0;
  auto alloc = [&](size_t bytes) -> void* {
    void* p = ws + off;
    off = (off + bytes + 255) & ~(size_t)255;
    return p;
  };
  int* cnt = (int*)alloc((size_t)N_NODES * sizeof(int));
  int* rowptr = (int*)alloc((size_t)(N_NODES + 1) * sizeof(int));
  int* nxt = (int*)alloc((size_t)N_NODES * sizeof(int));
  int* csr_src = (int*)alloc((size_t)E * sizeof(int));
  float* xl = (float*)alloc((size_t)N_NODES * 256 * sizeof(float));
  float* xr = (float*)alloc((size_t)N_NODES * 256 * sizeof(float));
  __hip_bfloat16* xb = (__hip_bfloat16*)alloc((size_t)N_NODES * 128 * 2);   // layer0 input
  __hip_bfloat16* curb = (__hip_bfloat16*)alloc((size_t)N_NODES * 256 * 2); // layer1/2 input
  __hip_bfloat16* wt[6];
  const int wk[6] = {128, 128, 256, 256, 256, 256};
  const int wo[6] = {256, 256, 256, 256, 128, 128};
  for (int i = 0; i < 6; ++i) wt[i] = (__hip_bfloat16*)alloc((size_t)wk[i] * wo[i] * 2);

  // ---- CSR by dst (stateless) ----
  zero_k<<<(N_NODES + 255) / 256, 256, 0, stream>>>(cnt, N_NODES);
  count_k<<<(E + 255) / 256, 256, 0, stream>>>(dst, E, cnt);
  scan_k<<<1, 1024, 0, stream>>>(cnt, rowptr, nxt, N_NODES);
  fill_k<<<(E + 255) / 256, 256, 0, stream>>>(src, dst, E, nxt, csr_src);

  // ---- conversions ----
  f2b_k<<<(N_NODES * 128 + 255) / 256, 256, 0, stream>>>(x, xb, N_NODES * 128);
  WtArgs wa;
  const float* wsrc[6] = {Wl[0], Wr[0], Wl[1], Wr[1], Wl[2], Wr[2]};
  for (int i = 0; i < 6; ++i) { wa.src[i] = wsrc[i]; wa.dst[i] = wt[i]; wa.K[i] = wk[i]; wa.O[i] = wo[i]; }
  wconv_k<<<dim3(64, 6), 256, 0, stream>>>(wa);

  // ---- layer 0: 128 -> 256 ----
  mfma_gemm_k<128, 256><<<dim3(157, 4, 2), 256, 0, stream>>>(
      (const ushort*)xb, (const ushort*)wt[0], (const ushort*)wt[1], xl, xr);
  agg3_k<256, false><<<N_NODES / 2, 256, 0, stream>>>(xl, xr, att[0], bia[0], rowptr, csr_src, curb);

  // ---- layer 1: 256 -> 256 ----
  mfma_gemm_k<256, 256><<<dim3(157, 4, 2), 256, 0, stream>>>(
      (const ushort*)curb, (const ushort*)wt[2], (const ushort*)wt[3], xl, xr);
  agg3_k<256, false><<<N_NODES / 2, 256, 0, stream>>>(xl, xr, att[1], bia[1], rowptr, csr_src, curb);

  // ---- layer 2: 256 -> 128 ----
  mfma_gemm_k<256, 128><<<dim3(157, 2, 2), 256, 0, stream>>>(
      (const ushort*)curb, (const ushort*)wt[4], (const ushort*)wt[5], xl, xr);
  agg3_k<128, true><<<N_NODES / 2, 256, 0, stream>>>(xl, xr, att[2], bia[2], rowptr, csr_src, d_out);
}

// Round 4
// 322.031 us; speedup vs baseline: 1.8411x; 1.3271x over previous
//
#include <hip/hip_runtime.h>
#include <hip/hip_bf16.h>
#include <math.h>

#define N_NODES 10000

typedef __attribute__((ext_vector_type(8))) short short8;
typedef __attribute__((ext_vector_type(8))) unsigned short ushort8;
typedef __attribute__((ext_vector_type(4))) unsigned short ushort4v;
typedef __attribute__((ext_vector_type(4))) float f32x4;

__device__ inline float b2f(unsigned short u) {
  union { unsigned int i; float f; } c;
  c.i = ((unsigned int)u) << 16;
  return c.f;
}
__device__ inline unsigned short f2bu(float v) {
  __hip_bfloat16 h = __float2bfloat16(v);
  return *(unsigned short*)&h;
}

// ---------------- CSR build ----------------

__global__ void zero_k(int* __restrict__ p, int n) {
  int i = blockIdx.x * blockDim.x + threadIdx.x;
  if (i < n) p[i] = 0;
}

__global__ void count_k(const int* __restrict__ dst, int E, int* __restrict__ cnt) {
  int i = blockIdx.x * blockDim.x + threadIdx.x;
  if (i < E) atomicAdd(&cnt[dst[i]], 1);
}

__global__ void scan_k(const int* __restrict__ cnt, int* __restrict__ rowptr,
                       int* __restrict__ nxt, int n) {
  __shared__ int lds[1024];
  __shared__ int carry_s;
  const int t = threadIdx.x;
  if (t == 0) carry_s = 0;
  __syncthreads();
  for (int base = 0; base < n; base += 1024) {
    int v = (base + t < n) ? cnt[base + t] : 0;
    lds[t] = v;
    __syncthreads();
    for (int off = 1; off < 1024; off <<= 1) {
      int add = (t >= off) ? lds[t - off] : 0;
      __syncthreads();
      lds[t] += add;
      __syncthreads();
    }
    int excl = lds[t] - v + carry_s;
    if (base + t < n) { rowptr[base + t] = excl; nxt[base + t] = excl; }
    int incl_last = lds[1023];
    __syncthreads();
    if (t == 0) carry_s += incl_last;
    __syncthreads();
  }
  if (t == 0) rowptr[n] = carry_s;
}

__global__ void fill_k(const int* __restrict__ src, const int* __restrict__ dst,
                       int E, int* __restrict__ nxt, int* __restrict__ csr_src) {
  int i = blockIdx.x * blockDim.x + threadIdx.x;
  if (i < E) {
    int pos = atomicAdd(&nxt[dst[i]], 1);
    csr_src[pos] = src[i];
  }
}

// ---------------- conversions ----------------

__global__ void f2b4_k(const float4* __restrict__ src, unsigned short* __restrict__ dst, int n4) {
  int i = blockIdx.x * blockDim.x + threadIdx.x;
  if (i < n4) {
    float4 v = src[i];
    ushort4v o;
    o.x = f2bu(v.x); o.y = f2bu(v.y); o.z = f2bu(v.z); o.w = f2bu(v.w);
    *(ushort4v*)&dst[4 * i] = o;
  }
}

// W [K][O] f32  ->  Wt [O][K] bf16, six matrices in one launch
struct WtArgs {
  const float* src[6];
  unsigned short* dst[6];
  int K[6];
  int O[6];
};

__global__ void wconv_k(WtArgs a) {
  const int m = blockIdx.y;
  const float* s = a.src[m];
  unsigned short* d = a.dst[m];
  const int K = a.K[m], O = a.O[m], n = K * O;
  for (int idx = blockIdx.x * 256 + threadIdx.x; idx < n; idx += gridDim.x * 256) {
    const int col = idx / K, k = idx - col * K;  // dst is [col][k]
    d[idx] = f2bu(s[k * O + col]);
  }
}

// ---------------- bf16 MFMA GEMM: Y[M,O] = Xb[M,K] @ Wt[O,K]^T, bf16 out ----

template <int K, int O>
__global__ void __launch_bounds__(256) mfma_gemm_k(
    const unsigned short* __restrict__ Xb, const unsigned short* __restrict__ WtL,
    const unsigned short* __restrict__ WtR, unsigned short* __restrict__ xlb,
    unsigned short* __restrict__ xrb) {
  const int wv = threadIdx.x >> 6, lane = threadIdx.x & 63;
  const int rowBase = blockIdx.x * 64 + wv * 16;
  const int colBase = blockIdx.y * 64;
  const unsigned short* __restrict__ Wt = blockIdx.z ? WtR : WtL;
  unsigned short* __restrict__ Y = blockIdx.z ? xrb : xlb;
  const int lr = lane & 15, lh = lane >> 4;

  int arow = rowBase + lr;
  if (arow >= N_NODES) arow = 0;  // clamp (loads only; stores guarded)
  const unsigned short* __restrict__ aptr = Xb + (size_t)arow * K + lh * 8;
  const unsigned short* __restrict__ bptr = Wt + (size_t)(colBase + lr) * K + lh * 8;

  f32x4 acc[4] = {f32x4{0,0,0,0}, f32x4{0,0,0,0}, f32x4{0,0,0,0}, f32x4{0,0,0,0}};
#pragma unroll
  for (int kt = 0; kt < K; kt += 32) {
    const short8 a = *(const short8*)(aptr + kt);
#pragma unroll
    for (int c = 0; c < 4; ++c) {
      const short8 b = *(const short8*)(bptr + (size_t)c * 16 * K + kt);
      acc[c] = __builtin_amdgcn_mfma_f32_16x16x32_bf16(a, b, acc[c], 0, 0, 0);
    }
  }
#pragma unroll
  for (int c = 0; c < 4; ++c) {
#pragma unroll
    for (int q = 0; q < 4; ++q) {
      const int r = rowBase + lh * 4 + q;
      if (r < N_NODES) Y[(size_t)r * O + colBase + c * 16 + lr] = f2bu(acc[c][q]);
    }
  }
}

// ---------------- per-dst-node online-softmax aggregation v4 ----------------
// bf16 gathers. 4 waves/block = 2 nodes x 2 half-lists. lane = (e_sub in
// [0,4) | cl in [0,16)); channels contiguous per lane. 3-slot row ring
// (issued 3 groups ahead), indices loaded 6 groups ahead; clamped over-run
// (invalid lanes/groups score -inf -> w=0 -> no-op) so no tail logic.
// leaky fold: p = 0.6*(sum a*t) + 0.4*(sum a*|t|).

template <int O, bool FINAL>
__global__ void __launch_bounds__(256, 4) agg4_k(
    const unsigned short* __restrict__ xlb, const unsigned short* __restrict__ xrb,
    const float* __restrict__ att, const float* __restrict__ bias,
    const int* __restrict__ rowptr, const int* __restrict__ csr_src,
    void* __restrict__ outp) {
  constexpr int NCH = O / 16;  // 16 or 8 channels per lane
  __shared__ float sm[2], ss[2], sacc[2][O];
  const int tid = threadIdx.x;
  const int wv = tid >> 6;
  const int lane = tid & 63;
  const int nloc = wv >> 1;
  const int half = wv & 1;
  const int node = blockIdx.x * 2 + nloc;
  const int e_sub = lane & 3;
  const int cl = lane >> 2;
  const int ch0 = cl * NCH;

  float av[NCH], xrv[NCH], acc[NCH];
#pragma unroll
  for (int k = 0; k < NCH; ++k) {
    av[k] = att[ch0 + k];
    xrv[k] = b2f(xrb[(size_t)node * O + ch0 + k]);
    acc[k] = 0.f;
  }
  const int beg = rowptr[node];
  const int end = rowptr[node + 1];
  const int h0 = (end - beg + 1) >> 1;
  const int b = half ? beg + h0 : beg;
  const int e_end = half ? end : beg + h0;

  float m = -INFINITY, s = 0.f;
  if (b < e_end) {
    const int e_last = e_end - 1;
    const int G = (e_end - b + 3) >> 2;
    const int G3 = ((G + 2) / 3) * 3;
    auto idx_of = [&](int g) -> int {
      int ei = b + 4 * g + e_sub;
      return csr_src[ei < e_last ? ei : e_last];
    };
    // row slots (bf16): lo = ch0..ch0+7, hi = ch0+8..ch0+15 (NCH==16 only)
    ushort8 lo0, hi0, lo1, hi1, lo2, hi2;
    {
      const int i0 = idx_of(0), i1 = idx_of(1), i2 = idx_of(2);
      const ushort8* r0 = (const ushort8*)(xlb + (size_t)i0 * O + ch0);
      const ushort8* r1 = (const ushort8*)(xlb + (size_t)i1 * O + ch0);
      const ushort8* r2 = (const ushort8*)(xlb + (size_t)i2 * O + ch0);
      lo0 = r0[0]; lo1 = r1[0]; lo2 = r2[0];
      if constexpr (NCH == 16) { hi0 = r0[1]; hi1 = r1[1]; hi2 = r2[1]; }
    }
    int jA = idx_of(3), jB = idx_of(4), jC = idx_of(5);

    auto step = [&](ushort8& lo, ushort8& hi, int& jref, int g, int gref) {
      // ---- score ----
      float p1 = 0.f, p2 = 0.f;
#pragma unroll
      for (int k = 0; k < 8; ++k) {
        const float t = b2f(lo[k]) + xrv[k];
        p1 = fmaf(av[k], t, p1);
        p2 = fmaf(av[k], fabsf(t), p2);
      }
      if constexpr (NCH == 16) {
#pragma unroll
        for (int k = 0; k < 8; ++k) {
          const float t = b2f(hi[k]) + xrv[8 + k];
          p1 = fmaf(av[8 + k], t, p1);
          p2 = fmaf(av[8 + k], fabsf(t), p2);
        }
      }
      float p = fmaf(0.6f, p1, 0.4f * p2);
      if (b + 4 * g + e_sub >= e_end) p = -INFINITY;
      p += __shfl_xor(p, 4, 64);
      p += __shfl_xor(p, 8, 64);
      p += __shfl_xor(p, 16, 64);
      p += __shfl_xor(p, 32, 64);
      float q = fmaxf(p, __shfl_xor(p, 1, 64));
      q = fmaxf(q, __shfl_xor(q, 2, 64));
      const float m_new = fmaxf(m, q);
      const float w = __expf(p - m_new);  // 0 for invalid
      float ws = w + __shfl_xor(w, 1, 64);
      ws += __shfl_xor(ws, 2, 64);
      if (m_new > m) {  // wave-uniform
        const float f = __expf(m - m_new);
        s *= f;
#pragma unroll
        for (int k = 0; k < NCH; ++k) acc[k] *= f;
        m = m_new;
      }
      s += ws;
#pragma unroll
      for (int k = 0; k < 8; ++k) acc[k] = fmaf(w, b2f(lo[k]), acc[k]);
      if constexpr (NCH == 16) {
#pragma unroll
        for (int k = 0; k < 8; ++k) acc[8 + k] = fmaf(w, b2f(hi[k]), acc[8 + k]);
      }
      // ---- reissue rows for g+3 into this slot ----
      const ushort8* rp = (const ushort8*)(xlb + (size_t)jref * O + ch0);
      lo = rp[0];
      if constexpr (NCH == 16) hi = rp[1];
      // ---- refill index for g+6 ----
      jref = idx_of(gref);
    };

    for (int g = 0; g < G3; g += 3) {
      step(lo0, hi0, jA, g, g + 6);
      step(lo1, hi1, jB, g + 1, g + 7);
      step(lo2, hi2, jC, g + 2, g + 8);
    }
  }
  // collapse 4 edge-residue copies
#pragma unroll
  for (int k = 0; k < NCH; ++k) {
    acc[k] += __shfl_xor(acc[k], 1, 64);
    acc[k] += __shfl_xor(acc[k], 2, 64);
  }
  if (half == 1) {
    if (lane == 0) { sm[nloc] = m; ss[nloc] = s; }
    if (e_sub == 0) {
#pragma unroll
      for (int k = 0; k < NCH; ++k) sacc[nloc][ch0 + k] = acc[k];
    }
  }
  __syncthreads();
  if (half == 0) {
    const float m1 = sm[nloc], s1 = ss[nloc];
    const float mt = fmaxf(m, m1);
    const float f0 = __expf(m - mt);
    const float f1 = __expf(m1 - mt);
    const float st = s * f0 + s1 * f1;
    const float inv = 1.f / (st + 1e-16f);
    if (e_sub == 0) {
#pragma unroll
      for (int k = 0; k < NCH; ++k) {
        const int ch = ch0 + k;
        float v = (acc[k] * f0 + sacc[nloc][ch] * f1) * inv + bias[ch];
        v = (v > 0.f) ? v : 0.f;  // relu
        if (FINAL) {
          ((float*)outp)[(size_t)node * O + ch] = 1.f / (1.f + __expf(-v));
        } else {
          ((unsigned short*)outp)[(size_t)node * O + ch] = f2bu(v);
        }
      }
    }
  }
}

// ---------------- launch ----------------

extern "C" void kernel_launch(void* const* d_in, const int* in_sizes, int n_in,
                              void* d_out, int out_size, void* d_ws, size_t ws_size,
                              hipStream_t stream) {
  const float* x = (const float*)d_in[0];
  const int* ei = (const int*)d_in[1];
  const int E = in_sizes[1] / 2;
  const int* src = ei;
  const int* dst = ei + E;
  const float* Wl[3] = {(const float*)d_in[2], (const float*)d_in[6], (const float*)d_in[10]};
  const float* Wr[3] = {(const float*)d_in[3], (const float*)d_in[7], (const float*)d_in[11]};
  const float* att[3] = {(const float*)d_in[4], (const float*)d_in[8], (const float*)d_in[12]};
  const float* bia[3] = {(const float*)d_in[5], (const float*)d_in[9], (const float*)d_in[13]};

  char* ws = (char*)d_ws;
  size_t off = 0;
  auto alloc = [&](size_t bytes) -> void* {
    void* p = ws + off;
    off = (off + bytes + 255) & ~(size_t)255;
    return p;
  };
  int* cnt = (int*)alloc((size_t)N_NODES * sizeof(int));
  int* rowptr = (int*)alloc((size_t)(N_NODES + 1) * sizeof(int));
  int* nxt = (int*)alloc((size_t)N_NODES * sizeof(int));
  int* csr_src = (int*)alloc((size_t)E * sizeof(int));
  unsigned short* xlb = (unsigned short*)alloc((size_t)N_NODES * 256 * 2);
  unsigned short* xrb = (unsigned short*)alloc((size_t)N_NODES * 256 * 2);
  unsigned short* xb = (unsigned short*)alloc((size_t)N_NODES * 128 * 2);    // layer0 input
  unsigned short* curb = (unsigned short*)alloc((size_t)N_NODES * 256 * 2);  // layer1/2 input
  unsigned short* wt[6];
  const int wk[6] = {128, 128, 256, 256, 256, 256};
  const int wo[6] = {256, 256, 256, 256, 128, 128};
  for (int i = 0; i < 6; ++i) wt[i] = (unsigned short*)alloc((size_t)wk[i] * wo[i] * 2);

  // ---- CSR by dst (stateless) ----
  zero_k<<<(N_NODES + 255) / 256, 256, 0, stream>>>(cnt, N_NODES);
  count_k<<<(E + 255) / 256, 256, 0, stream>>>(dst, E, cnt);
  scan_k<<<1, 1024, 0, stream>>>(cnt, rowptr, nxt, N_NODES);
  fill_k<<<(E + 255) / 256, 256, 0, stream>>>(src, dst, E, nxt, csr_src);

  // ---- conversions ----
  f2b4_k<<<(N_NODES * 128 / 4 + 255) / 256, 256, 0, stream>>>((const float4*)x, xb,
                                                              N_NODES * 128 / 4);
  WtArgs wa;
  const float* wsrc[6] = {Wl[0], Wr[0], Wl[1], Wr[1], Wl[2], Wr[2]};
  for (int i = 0; i < 6; ++i) { wa.src[i] = wsrc[i]; wa.dst[i] = wt[i]; wa.K[i] = wk[i]; wa.O[i] = wo[i]; }
  wconv_k<<<dim3(64, 6), 256, 0, stream>>>(wa);

  // ---- layer 0: 128 -> 256 ----
  mfma_gemm_k<128, 256><<<dim3(157, 4, 2), 256, 0, stream>>>(xb, wt[0], wt[1], xlb, xrb);
  agg4_k<256, false><<<N_NODES / 2, 256, 0, stream>>>(xlb, xrb, att[0], bia[0], rowptr, csr_src, curb);

  // ---- layer 1: 256 -> 256 ----
  mfma_gemm_k<256, 256><<<dim3(157, 4, 2), 256, 0, stream>>>(curb, wt[2], wt[3], xlb, xrb);
  agg4_k<256, false><<<N_NODES / 2, 256, 0, stream>>>(xlb, xrb, att[1], bia[1], rowptr, csr_src, curb);

  // ---- layer 2: 256 -> 128 ----
  mfma_gemm_k<256, 128><<<dim3(157, 2, 2), 256, 0, stream>>>(curb, wt[4], wt[5], xlb, xrb);
  agg4_k<128, true><<<N_NODES / 2, 256, 0, stream>>>(xlb, xrb, att[2], bia[2], rowptr, csr_src, d_out);
}